// Round 3
// baseline (799.166 us; speedup 1.0000x reference)
//
#include <hip/hip_runtime.h>
#include <hip/hip_bf16.h>
#include <stdint.h>

// MultiheadSelfAttention: B=2, S=4096, D=512, H=8, HD=64
// v3: flash attention with in-block split-K (8 waves: 4 q-waves x 2 k-halves,
// LDS merge at end, ONE barrier per block), and ds_bpermute register transpose
// for P (C-layout -> B-operand) -- zero LDS round trips in the k-loop.

typedef __attribute__((ext_vector_type(8))) short short8;
typedef __attribute__((ext_vector_type(4))) float floatx4;

#define MFMA(a, b, c) __builtin_amdgcn_mfma_f32_16x16x32_bf16((a), (b), (c), 0, 0, 0)

__device__ __forceinline__ short f2bf(float f) {
    union { float f; uint32_t u; } c; c.f = f;
    uint32_t u = c.u;
    u += 0x7fffu + ((u >> 16) & 1u);   // RNE
    return (short)(u >> 16);
}
__device__ __forceinline__ float bf2f(short s) {
    union { float f; uint32_t u; } c; c.u = ((uint32_t)(uint16_t)s) << 16;
    return c.f;
}
__device__ __forceinline__ int pack2(float a, float b) {
    return (int)(uint16_t)f2bf(a) | ((int)(uint16_t)f2bf(b) << 16);
}

// ---------------------------------------------------------------- converts
__global__ void cvt_bf16(const float* __restrict__ src, short* __restrict__ dst, int n) {
    int i = (blockIdx.x * 256 + threadIdx.x) * 8;
    if (i >= n) return;
    floatx4 v0 = *(const floatx4*)(src + i);
    floatx4 v1 = *(const floatx4*)(src + i + 4);
    short8 o;
    #pragma unroll
    for (int j = 0; j < 4; ++j) { o[j] = f2bf(v0[j]); o[4 + j] = f2bf(v1[j]); }
    *(short8*)(dst + i) = o;
}

__global__ void cvt3_bf16(const float* __restrict__ s0, const float* __restrict__ s1,
                          const float* __restrict__ s2, short* __restrict__ d0,
                          short* __restrict__ d1, short* __restrict__ d2) {
    int idx = blockIdx.x * 256 + threadIdx.x;
    int which = idx >> 15;
    int i = (idx & 32767) * 8;
    const float* src = which == 0 ? s0 : which == 1 ? s1 : s2;
    short* dst = which == 0 ? d0 : which == 1 ? d1 : d2;
    floatx4 v0 = *(const floatx4*)(src + i);
    floatx4 v1 = *(const floatx4*)(src + i + 4);
    short8 o;
    #pragma unroll
    for (int j = 0; j < 4; ++j) { o[j] = f2bf(v0[j]); o[4 + j] = f2bf(v1[j]); }
    *(short8*)(dst + i) = o;
}

__global__ void cvt_split(const float* __restrict__ src, short* __restrict__ hi,
                          short* __restrict__ lo, int n) {
    int i = (blockIdx.x * 256 + threadIdx.x) * 8;
    if (i >= n) return;
    floatx4 v0 = *(const floatx4*)(src + i);
    floatx4 v1 = *(const floatx4*)(src + i + 4);
    short8 h, l;
    #pragma unroll
    for (int j = 0; j < 4; ++j) {
        short hh = f2bf(v0[j]); h[j] = hh; l[j] = f2bf(v0[j] - bf2f(hh));
        short hh1 = f2bf(v1[j]); h[4 + j] = hh1; l[4 + j] = f2bf(v1[j] - bf2f(hh1));
    }
    *(short8*)(hi + i) = h;
    *(short8*)(lo + i) = l;
}

// ---------------------------------------------------------------- QKV GEMM
__global__ __launch_bounds__(256) void qkv_gemm(
    const short* __restrict__ Xb,
    const short* __restrict__ Wq, const short* __restrict__ Wk, const short* __restrict__ Wv,
    const float* __restrict__ bq, const float* __restrict__ bk, const float* __restrict__ bv,
    short* __restrict__ Qo, short* __restrict__ Ko, short* __restrict__ VTo)
{
    const int lane = threadIdx.x & 63, wave = threadIdx.x >> 6;
    const int col = lane & 15, quad = lane >> 4;
    const int wm = wave & 1, wn = wave >> 1;
    const int m0 = blockIdx.x * 64 + wm * 32;
    const int nblk = blockIdx.y * 64;
    const int which = nblk >> 9;                 // 0=Q,1=K,2=V
    const int nloc = (nblk & 511) + wn * 32;
    const short* W = which == 0 ? Wq : which == 1 ? Wk : Wv;
    const float* bias = which == 0 ? bq : which == 1 ? bk : bv;
    const float oscale = which == 0 ? 0.1803368801111204f : 1.0f;  // 0.125*log2e

    floatx4 acc[2][2] = {};
    const short* a0p = Xb + (size_t)(m0 + col) * 512 + quad * 8;
    const short* b0p = W + (size_t)(nloc + col) * 512 + quad * 8;
    #pragma unroll 4
    for (int k = 0; k < 512; k += 32) {
        short8 a0 = *(const short8*)(a0p + k);
        short8 a1 = *(const short8*)(a0p + 16 * 512 + k);
        short8 b0 = *(const short8*)(b0p + k);
        short8 b1 = *(const short8*)(b0p + 16 * 512 + k);
        acc[0][0] = MFMA(a0, b0, acc[0][0]);
        acc[0][1] = MFMA(a0, b1, acc[0][1]);
        acc[1][0] = MFMA(a1, b0, acc[1][0]);
        acc[1][1] = MFMA(a1, b1, acc[1][1]);
    }
    #pragma unroll
    for (int im = 0; im < 2; ++im)
        #pragma unroll
        for (int in = 0; in < 2; ++in)
            #pragma unroll
            for (int r = 0; r < 4; ++r) {
                int m = m0 + im * 16 + quad * 4 + r;
                int n = nloc + in * 16 + col;
                float v = (acc[im][in][r] + bias[n]) * oscale;
                int b = m >> 12, s = m & 4095;
                int h = n >> 6, hd = n & 63;
                int bh = b * 8 + h;
                short bv16 = f2bf(v);
                if (which == 0)      Qo[((size_t)bh * 4096 + s) * 64 + hd] = bv16;
                else if (which == 1) Ko[((size_t)bh * 4096 + s) * 64 + hd] = bv16;
                else                 VTo[((size_t)bh * 64 + hd) * 4096 + s] = bv16;
            }
}

// ---------------------------------------------------------------- flash attn
// Grid (S/64, BH), 512 threads = 8 waves. Wave w: q-rows q0+16*(w&3),
// k-half (w>>2)*2048. Per 64-key tile: S^T via MFMA (lane: q=col,
// t=nt*16+quad*4+r), per-lane softmax (2 shfl), P transpose to B-operand via
// 16x ds_bpermute (no LDS round trip, no barriers), PV O^T += V^T P^T.
// End: halves merged through LDS with one __syncthreads.
__global__ __launch_bounds__(512, 8) void flash_attn(
    const short* __restrict__ Q, const short* __restrict__ Kk,
    const short* __restrict__ VT,
    short* __restrict__ Ahi, short* __restrict__ Alo)
{
    __shared__ float Osh[4][16 * 68];       // stride 68 floats: 2-way max conflict
    __shared__ float Msh[4][16], Lsh[4][16];
    const int lane = threadIdx.x & 63, wave = threadIdx.x >> 6;
    const int col = lane & 15, quad = lane >> 4;
    const int bh = blockIdx.y, b = bh >> 3, h = bh & 7;
    const int qw = wave & 3, kz = wave >> 2;
    const int q0 = blockIdx.x * 64 + qw * 16;
    const size_t base = (size_t)bh * 4096 * 64;
    const size_t vbase = (size_t)bh * 64 * 4096;

    // Q as B-operand (pre-scaled by 0.125*log2e in qkv epilogue)
    const short* qptr = Q + base + (size_t)(q0 + col) * 64 + quad * 8;
    short8 qf0 = *(const short8*)(qptr);
    short8 qf1 = *(const short8*)(qptr + 32);

    // bpermute source-lane byte addresses (see mapping note above)
    const int pa0 = (col + 32 * (quad & 1)) * 4;
    const int pa1 = pa0 + 64;
    const bool hi_t = (lane & 32) != 0;

    floatx4 o[4] = {};
    float m_i = -1e30f, l_i = 0.f;

    const int kbeg = kz * 2048, kend = kbeg + 2048;
    for (int kk = kbeg; kk < kend; kk += 64) {
        // ---- S^T = K · Q^T
        floatx4 sa[4];
        #pragma unroll
        for (int nt = 0; nt < 4; ++nt) {
            const short* kptr = Kk + base + (size_t)(kk + nt * 16 + col) * 64 + quad * 8;
            short8 k0 = *(const short8*)(kptr);
            short8 k1 = *(const short8*)(kptr + 32);
            floatx4 zz = {0.f, 0.f, 0.f, 0.f};
            zz = MFMA(k0, qf0, zz);
            sa[nt] = MFMA(k1, qf1, zz);
        }
        // ---- online softmax (per-lane rows, 2 shfl)
        float tmax = sa[0][0];
        #pragma unroll
        for (int nt = 0; nt < 4; ++nt)
            #pragma unroll
            for (int r = 0; r < 4; ++r) tmax = fmaxf(tmax, sa[nt][r]);
        tmax = fmaxf(tmax, __shfl_xor(tmax, 16));
        tmax = fmaxf(tmax, __shfl_xor(tmax, 32));
        float newm = fmaxf(m_i, tmax);
        float alpha = exp2f(m_i - newm);
        m_i = newm;
        float rsum = 0.f;
        int pk[4][2];
        #pragma unroll
        for (int nt = 0; nt < 4; ++nt) {
            float p0 = exp2f(sa[nt][0] - newm);
            float p1 = exp2f(sa[nt][1] - newm);
            float p2 = exp2f(sa[nt][2] - newm);
            float p3 = exp2f(sa[nt][3] - newm);
            rsum += (p0 + p1) + (p2 + p3);
            pk[nt][0] = pack2(p0, p1);
            pk[nt][1] = pack2(p2, p3);
        }
        rsum += __shfl_xor(rsum, 16);
        rsum += __shfl_xor(rsum, 32);
        l_i = l_i * alpha + rsum;

        // ---- V loads (independent; in flight during transpose)
        short8 v0[4], v1[4];
        #pragma unroll
        for (int mt = 0; mt < 4; ++mt) {
            const short* vptr = VT + vbase + (size_t)(mt * 16 + col) * 4096 + kk + quad * 8;
            v0[mt] = *(const short8*)(vptr);
            v1[mt] = *(const short8*)(vptr + 32);
        }

        // ---- P^T C-layout -> B-operand via register bpermute
        // target reg j of chunk c: t = 32c + quad*8 + {2j,2j+1}; source lane
        // col + 16*(2*(quad&1) + (j>>1)), value pk[2c + (quad>>1)][j&1]
        short8 pf[2];
        #pragma unroll
        for (int c = 0; c < 2; ++c) {
            union { int i[4]; short8 s; } u;
            int r0, r1;
            r0 = __builtin_amdgcn_ds_bpermute(pa0, pk[2 * c][0]);
            r1 = __builtin_amdgcn_ds_bpermute(pa0, pk[2 * c + 1][0]);
            u.i[0] = hi_t ? r1 : r0;
            r0 = __builtin_amdgcn_ds_bpermute(pa0, pk[2 * c][1]);
            r1 = __builtin_amdgcn_ds_bpermute(pa0, pk[2 * c + 1][1]);
            u.i[1] = hi_t ? r1 : r0;
            r0 = __builtin_amdgcn_ds_bpermute(pa1, pk[2 * c][0]);
            r1 = __builtin_amdgcn_ds_bpermute(pa1, pk[2 * c + 1][0]);
            u.i[2] = hi_t ? r1 : r0;
            r0 = __builtin_amdgcn_ds_bpermute(pa1, pk[2 * c][1]);
            r1 = __builtin_amdgcn_ds_bpermute(pa1, pk[2 * c + 1][1]);
            u.i[3] = hi_t ? r1 : r0;
            pf[c] = u.s;
        }

        #pragma unroll
        for (int mt = 0; mt < 4; ++mt)
            #pragma unroll
            for (int r = 0; r < 4; ++r) o[mt][r] *= alpha;

        // ---- O^T += V^T · P^T
        #pragma unroll
        for (int mt = 0; mt < 4; ++mt) {
            o[mt] = MFMA(v0[mt], pf[0], o[mt]);
            o[mt] = MFMA(v1[mt], pf[1], o[mt]);
        }
    }

    // ---- merge the two k-halves through LDS (one barrier)
    if (kz == 1) {
        #pragma unroll
        for (int mt = 0; mt < 4; ++mt)
            *(floatx4*)&Osh[qw][col * 68 + mt * 16 + quad * 4] = o[mt];
        if (quad == 0) { Msh[qw][col] = m_i; Lsh[qw][col] = l_i; }
    }
    __syncthreads();
    if (kz == 0) {
        float m2 = Msh[qw][col], l2 = Lsh[qw][col];
        float M = fmaxf(m_i, m2);
        float aa = exp2f(m_i - M), ab = exp2f(m2 - M);
        float linv = 1.0f / (aa * l_i + ab * l2);
        size_t rowoff = (size_t)(b * 4096 + q0 + col) * 512 + h * 64;
        #pragma unroll
        for (int mt = 0; mt < 4; ++mt) {
            floatx4 o2 = *(const floatx4*)&Osh[qw][col * 68 + mt * 16 + quad * 4];
            float w0 = (aa * o[mt][0] + ab * o2[0]) * linv;
            float w1 = (aa * o[mt][1] + ab * o2[1]) * linv;
            float w2 = (aa * o[mt][2] + ab * o2[2]) * linv;
            float w3 = (aa * o[mt][3] + ab * o2[3]) * linv;
            int2 hi, lo;
            hi.x = pack2(w0, w1); hi.y = pack2(w2, w3);
            lo.x = pack2(w0 - bf2f(f2bf(w0)), w1 - bf2f(f2bf(w1)));
            lo.y = pack2(w2 - bf2f(f2bf(w2)), w3 - bf2f(f2bf(w3)));
            *(int2*)(Ahi + rowoff + mt * 16 + quad * 4) = hi;
            *(int2*)(Alo + rowoff + mt * 16 + quad * 4) = lo;
        }
    }
}

// ---------------------------------------------------------------- out GEMM
__global__ __launch_bounds__(256) void out_gemm(
    const short* __restrict__ Ahi, const short* __restrict__ Alo,
    const short* __restrict__ Whi, const short* __restrict__ Wlo,
    const float* __restrict__ bo, float* __restrict__ Out)
{
    const int lane = threadIdx.x & 63, wave = threadIdx.x >> 6;
    const int col = lane & 15, quad = lane >> 4;
    const int wm = wave & 1, wn = wave >> 1;
    const int m0 = blockIdx.x * 64 + wm * 32;
    const int n0 = blockIdx.y * 64 + wn * 32;
    floatx4 acc[2][2] = {};
    const short* ahp = Ahi + (size_t)(m0 + col) * 512 + quad * 8;
    const short* alp = Alo + (size_t)(m0 + col) * 512 + quad * 8;
    const short* bhp = Whi + (size_t)(n0 + col) * 512 + quad * 8;
    const short* blp = Wlo + (size_t)(n0 + col) * 512 + quad * 8;
    #pragma unroll 2
    for (int k = 0; k < 512; k += 32) {
        short8 ah0 = *(const short8*)(ahp + k);
        short8 ah1 = *(const short8*)(ahp + 16 * 512 + k);
        short8 al0 = *(const short8*)(alp + k);
        short8 al1 = *(const short8*)(alp + 16 * 512 + k);
        short8 bh0 = *(const short8*)(bhp + k);
        short8 bh1 = *(const short8*)(bhp + 16 * 512 + k);
        short8 bl0 = *(const short8*)(blp + k);
        short8 bl1 = *(const short8*)(blp + 16 * 512 + k);
        acc[0][0] = MFMA(ah0, bh0, acc[0][0]);
        acc[0][0] = MFMA(ah0, bl0, acc[0][0]);
        acc[0][0] = MFMA(al0, bh0, acc[0][0]);
        acc[0][1] = MFMA(ah0, bh1, acc[0][1]);
        acc[0][1] = MFMA(ah0, bl1, acc[0][1]);
        acc[0][1] = MFMA(al0, bh1, acc[0][1]);
        acc[1][0] = MFMA(ah1, bh0, acc[1][0]);
        acc[1][0] = MFMA(ah1, bl0, acc[1][0]);
        acc[1][0] = MFMA(al1, bh0, acc[1][0]);
        acc[1][1] = MFMA(ah1, bh1, acc[1][1]);
        acc[1][1] = MFMA(ah1, bl1, acc[1][1]);
        acc[1][1] = MFMA(al1, bh1, acc[1][1]);
    }
    #pragma unroll
    for (int i = 0; i < 2; ++i)
        #pragma unroll
        for (int j = 0; j < 2; ++j)
            #pragma unroll
            for (int r = 0; r < 4; ++r) {
                int m = m0 + i * 16 + quad * 4 + r;
                int n = n0 + j * 16 + col;
                Out[(size_t)m * 512 + n] = acc[i][j][r] + bo[n];
            }
}

// ---------------------------------------------------------------- launcher
extern "C" void kernel_launch(void* const* d_in, const int* in_sizes, int n_in,
                              void* d_out, int out_size, void* d_ws, size_t ws_size,
                              hipStream_t stream) {
    (void)in_sizes; (void)n_in; (void)out_size; (void)ws_size;
    const float* x   = (const float*)d_in[0];
    const float* W_q = (const float*)d_in[1];
    const float* b_q = (const float*)d_in[2];
    const float* W_k = (const float*)d_in[3];
    const float* b_k = (const float*)d_in[4];
    const float* W_v = (const float*)d_in[5];
    const float* b_v = (const float*)d_in[6];
    const float* W_o = (const float*)d_in[7];
    const float* b_o = (const float*)d_in[8];
    float* out = (float*)d_out;
    char* ws = (char*)d_ws;

    short* Xb   = (short*)(ws + 0);          // 8192*512*2  = 8,388,608
    short* Wqb  = (short*)(ws + 8388608);
    short* Wkb  = (short*)(ws + 8912896);
    short* Wvb  = (short*)(ws + 9437184);
    short* Wohi = (short*)(ws + 9961472);
    short* Wolo = (short*)(ws + 10485760);
    short* Qb   = (short*)(ws + 11010048);   // [16][4096][64]
    short* Kb   = (short*)(ws + 19398656);
    short* VTb  = (short*)(ws + 27787264);   // [16][64][4096]
    short* Ahi  = (short*)(ws + 36175872);   // [8192][512]
    short* Alo  = (short*)(ws + 44564480);   // end 52,953,088 bytes

    cvt_bf16<<<dim3(2048), dim3(256), 0, stream>>>(x, Xb, 4194304);
    cvt3_bf16<<<dim3(384), dim3(256), 0, stream>>>(W_q, W_k, W_v, Wqb, Wkb, Wvb);
    cvt_split<<<dim3(128), dim3(256), 0, stream>>>(W_o, Wohi, Wolo, 262144);
    qkv_gemm<<<dim3(128, 24), dim3(256), 0, stream>>>(Xb, Wqb, Wkb, Wvb, b_q, b_k, b_v, Qb, Kb, VTb);
    flash_attn<<<dim3(64, 16), dim3(512), 0, stream>>>(Qb, Kb, VTb, Ahi, Alo);
    out_gemm<<<dim3(128, 8), dim3(256), 0, stream>>>(Ahi, Alo, Wohi, Wolo, b_o, out);
}

// Round 4
// 467.596 us; speedup vs baseline: 1.7091x; 1.7091x over previous
//
#include <hip/hip_runtime.h>
#include <hip/hip_bf16.h>
#include <stdint.h>

// MultiheadSelfAttention: B=2, S=4096, D=512, H=8, HD=64
// v4: flash attention, M=32 q-rows/wave (2 q-fragments), full-K per wave,
// zero LDS / zero barriers, K-tile prefetch. Rationale: per-iteration vector
// memory traffic (K+V tiles) per q-row is the bottleneck (TA request rate);
// M=32 halves total traffic vs M=16 (4.3GB -> 2.1GB).

typedef __attribute__((ext_vector_type(8))) short short8;
typedef __attribute__((ext_vector_type(4))) float floatx4;

#define MFMA(a, b, c) __builtin_amdgcn_mfma_f32_16x16x32_bf16((a), (b), (c), 0, 0, 0)

__device__ __forceinline__ short f2bf(float f) {
    union { float f; uint32_t u; } c; c.f = f;
    uint32_t u = c.u;
    u += 0x7fffu + ((u >> 16) & 1u);   // RNE
    return (short)(u >> 16);
}
__device__ __forceinline__ float bf2f(short s) {
    union { float f; uint32_t u; } c; c.u = ((uint32_t)(uint16_t)s) << 16;
    return c.f;
}
__device__ __forceinline__ int pack2(float a, float b) {
    return (int)(uint16_t)f2bf(a) | ((int)(uint16_t)f2bf(b) << 16);
}

// ---------------------------------------------------------------- converts
__global__ void cvt_bf16(const float* __restrict__ src, short* __restrict__ dst, int n) {
    int i = (blockIdx.x * 256 + threadIdx.x) * 8;
    if (i >= n) return;
    floatx4 v0 = *(const floatx4*)(src + i);
    floatx4 v1 = *(const floatx4*)(src + i + 4);
    short8 o;
    #pragma unroll
    for (int j = 0; j < 4; ++j) { o[j] = f2bf(v0[j]); o[4 + j] = f2bf(v1[j]); }
    *(short8*)(dst + i) = o;
}

__global__ void cvt3_bf16(const float* __restrict__ s0, const float* __restrict__ s1,
                          const float* __restrict__ s2, short* __restrict__ d0,
                          short* __restrict__ d1, short* __restrict__ d2) {
    int idx = blockIdx.x * 256 + threadIdx.x;
    int which = idx >> 15;
    int i = (idx & 32767) * 8;
    const float* src = which == 0 ? s0 : which == 1 ? s1 : s2;
    short* dst = which == 0 ? d0 : which == 1 ? d1 : d2;
    floatx4 v0 = *(const floatx4*)(src + i);
    floatx4 v1 = *(const floatx4*)(src + i + 4);
    short8 o;
    #pragma unroll
    for (int j = 0; j < 4; ++j) { o[j] = f2bf(v0[j]); o[4 + j] = f2bf(v1[j]); }
    *(short8*)(dst + i) = o;
}

__global__ void cvt_split(const float* __restrict__ src, short* __restrict__ hi,
                          short* __restrict__ lo, int n) {
    int i = (blockIdx.x * 256 + threadIdx.x) * 8;
    if (i >= n) return;
    floatx4 v0 = *(const floatx4*)(src + i);
    floatx4 v1 = *(const floatx4*)(src + i + 4);
    short8 h, l;
    #pragma unroll
    for (int j = 0; j < 4; ++j) {
        short hh = f2bf(v0[j]); h[j] = hh; l[j] = f2bf(v0[j] - bf2f(hh));
        short hh1 = f2bf(v1[j]); h[4 + j] = hh1; l[4 + j] = f2bf(v1[j] - bf2f(hh1));
    }
    *(short8*)(hi + i) = h;
    *(short8*)(lo + i) = l;
}

// ---------------------------------------------------------------- QKV GEMM
__global__ __launch_bounds__(256) void qkv_gemm(
    const short* __restrict__ Xb,
    const short* __restrict__ Wq, const short* __restrict__ Wk, const short* __restrict__ Wv,
    const float* __restrict__ bq, const float* __restrict__ bk, const float* __restrict__ bv,
    short* __restrict__ Qo, short* __restrict__ Ko, short* __restrict__ VTo)
{
    const int lane = threadIdx.x & 63, wave = threadIdx.x >> 6;
    const int col = lane & 15, quad = lane >> 4;
    const int wm = wave & 1, wn = wave >> 1;
    const int m0 = blockIdx.x * 64 + wm * 32;
    const int nblk = blockIdx.y * 64;
    const int which = nblk >> 9;                 // 0=Q,1=K,2=V
    const int nloc = (nblk & 511) + wn * 32;
    const short* W = which == 0 ? Wq : which == 1 ? Wk : Wv;
    const float* bias = which == 0 ? bq : which == 1 ? bk : bv;
    const float oscale = which == 0 ? 0.1803368801111204f : 1.0f;  // 0.125*log2e

    floatx4 acc[2][2] = {};
    const short* a0p = Xb + (size_t)(m0 + col) * 512 + quad * 8;
    const short* b0p = W + (size_t)(nloc + col) * 512 + quad * 8;
    #pragma unroll 4
    for (int k = 0; k < 512; k += 32) {
        short8 a0 = *(const short8*)(a0p + k);
        short8 a1 = *(const short8*)(a0p + 16 * 512 + k);
        short8 b0 = *(const short8*)(b0p + k);
        short8 b1 = *(const short8*)(b0p + 16 * 512 + k);
        acc[0][0] = MFMA(a0, b0, acc[0][0]);
        acc[0][1] = MFMA(a0, b1, acc[0][1]);
        acc[1][0] = MFMA(a1, b0, acc[1][0]);
        acc[1][1] = MFMA(a1, b1, acc[1][1]);
    }
    #pragma unroll
    for (int im = 0; im < 2; ++im)
        #pragma unroll
        for (int in = 0; in < 2; ++in)
            #pragma unroll
            for (int r = 0; r < 4; ++r) {
                int m = m0 + im * 16 + quad * 4 + r;
                int n = nloc + in * 16 + col;
                float v = (acc[im][in][r] + bias[n]) * oscale;
                int b = m >> 12, s = m & 4095;
                int h = n >> 6, hd = n & 63;
                int bh = b * 8 + h;
                short bv16 = f2bf(v);
                if (which == 0)      Qo[((size_t)bh * 4096 + s) * 64 + hd] = bv16;
                else if (which == 1) Ko[((size_t)bh * 4096 + s) * 64 + hd] = bv16;
                else                 VTo[((size_t)bh * 64 + hd) * 4096 + s] = bv16;
            }
}

// ---------------------------------------------------------------- flash attn
// Grid (S/128, BH), 256 threads = 4 waves, each wave: 32 q-rows, ALL keys.
// Per 64-key tile: S^T = K.Q^T via MFMA (lane: q=col, key=quad*4+r), per-lane
// softmax (2 shfl per qf), bpermute register transpose of P, O^T += V^T.P^T.
// Next K tile prefetched during softmax. No LDS, no barriers.
__device__ __forceinline__ void softmax_qf(
    floatx4* sa, float& m_i, float& l_i, float& alpha,
    int pa0, int pa1, bool hi_t, short8* pf)
{
    float tmax = sa[0][0];
    #pragma unroll
    for (int nt = 0; nt < 4; ++nt)
        #pragma unroll
        for (int r = 0; r < 4; ++r) tmax = fmaxf(tmax, sa[nt][r]);
    tmax = fmaxf(tmax, __shfl_xor(tmax, 16));
    tmax = fmaxf(tmax, __shfl_xor(tmax, 32));
    float newm = fmaxf(m_i, tmax);
    alpha = exp2f(m_i - newm);
    m_i = newm;
    float rsum = 0.f;
    int pk[4][2];
    #pragma unroll
    for (int nt = 0; nt < 4; ++nt) {
        float p0 = exp2f(sa[nt][0] - newm);
        float p1 = exp2f(sa[nt][1] - newm);
        float p2 = exp2f(sa[nt][2] - newm);
        float p3 = exp2f(sa[nt][3] - newm);
        rsum += (p0 + p1) + (p2 + p3);
        pk[nt][0] = pack2(p0, p1);
        pk[nt][1] = pack2(p2, p3);
    }
    rsum += __shfl_xor(rsum, 16);
    rsum += __shfl_xor(rsum, 32);
    l_i = l_i * alpha + rsum;
    // C-layout P^T -> B-operand fragments via register bpermute
    #pragma unroll
    for (int c = 0; c < 2; ++c) {
        union { int i[4]; short8 s; } u;
        int r0, r1;
        r0 = __builtin_amdgcn_ds_bpermute(pa0, pk[2 * c][0]);
        r1 = __builtin_amdgcn_ds_bpermute(pa0, pk[2 * c + 1][0]);
        u.i[0] = hi_t ? r1 : r0;
        r0 = __builtin_amdgcn_ds_bpermute(pa0, pk[2 * c][1]);
        r1 = __builtin_amdgcn_ds_bpermute(pa0, pk[2 * c + 1][1]);
        u.i[1] = hi_t ? r1 : r0;
        r0 = __builtin_amdgcn_ds_bpermute(pa1, pk[2 * c][0]);
        r1 = __builtin_amdgcn_ds_bpermute(pa1, pk[2 * c + 1][0]);
        u.i[2] = hi_t ? r1 : r0;
        r0 = __builtin_amdgcn_ds_bpermute(pa1, pk[2 * c][1]);
        r1 = __builtin_amdgcn_ds_bpermute(pa1, pk[2 * c + 1][1]);
        u.i[3] = hi_t ? r1 : r0;
        pf[c] = u.s;
    }
}

__global__ __launch_bounds__(256, 2) void flash_attn(
    const short* __restrict__ Q, const short* __restrict__ Kk,
    const short* __restrict__ VT,
    short* __restrict__ Ahi, short* __restrict__ Alo)
{
    const int lane = threadIdx.x & 63, wave = threadIdx.x >> 6;
    const int col = lane & 15, quad = lane >> 4;
    const int bh = blockIdx.y, b = bh >> 3, h = bh & 7;
    const int q0 = blockIdx.x * 128 + wave * 32;
    const size_t base = (size_t)bh * 4096 * 64;
    const size_t vbase = (size_t)bh * 64 * 4096;

    // two q-fragments (B-operand), pre-scaled by 0.125*log2e in qkv epilogue
    const short* qptr = Q + base + (size_t)(q0 + col) * 64 + quad * 8;
    short8 qA0 = *(const short8*)(qptr);
    short8 qA1 = *(const short8*)(qptr + 32);
    short8 qB0 = *(const short8*)(qptr + 16 * 64);
    short8 qB1 = *(const short8*)(qptr + 16 * 64 + 32);

    const int pa0 = (col + 32 * (quad & 1)) * 4;
    const int pa1 = pa0 + 64;
    const bool hi_t = (lane & 32) != 0;

    floatx4 oA[4] = {}, oB[4] = {};
    float mA = -1e30f, lA = 0.f, mB = -1e30f, lB = 0.f;

    // preload K tile 0
    short8 kc0[4], kc1[4];
    #pragma unroll
    for (int nt = 0; nt < 4; ++nt) {
        const short* kptr = Kk + base + (size_t)(nt * 16 + col) * 64 + quad * 8;
        kc0[nt] = *(const short8*)(kptr);
        kc1[nt] = *(const short8*)(kptr + 32);
    }

    for (int kk = 0; kk < 4096; kk += 64) {
        // ---- S^T = K · Q^T for both q-fragments
        floatx4 saA[4], saB[4];
        #pragma unroll
        for (int nt = 0; nt < 4; ++nt) {
            floatx4 z = {0.f, 0.f, 0.f, 0.f};
            z = MFMA(kc0[nt], qA0, z);
            saA[nt] = MFMA(kc1[nt], qA1, z);
            floatx4 z2 = {0.f, 0.f, 0.f, 0.f};
            z2 = MFMA(kc0[nt], qB0, z2);
            saB[nt] = MFMA(kc1[nt], qB1, z2);
        }
        // ---- prefetch next K tile (wrapped addr; hidden under softmax)
        const int kn = (kk + 64) & 4095;
        short8 kn0[4], kn1[4];
        #pragma unroll
        for (int nt = 0; nt < 4; ++nt) {
            const short* kptr = Kk + base + (size_t)(kn + nt * 16 + col) * 64 + quad * 8;
            kn0[nt] = *(const short8*)(kptr);
            kn1[nt] = *(const short8*)(kptr + 32);
        }
        // ---- V loads (independent; in flight during softmax/transpose)
        short8 v0[4], v1[4];
        #pragma unroll
        for (int mt = 0; mt < 4; ++mt) {
            const short* vptr = VT + vbase + (size_t)(mt * 16 + col) * 4096 + kk + quad * 8;
            v0[mt] = *(const short8*)(vptr);
            v1[mt] = *(const short8*)(vptr + 32);
        }
        // ---- online softmax + P transpose, per q-fragment
        float alphaA, alphaB;
        short8 pfA[2], pfB[2];
        softmax_qf(saA, mA, lA, alphaA, pa0, pa1, hi_t, pfA);
        softmax_qf(saB, mB, lB, alphaB, pa0, pa1, hi_t, pfB);
        #pragma unroll
        for (int mt = 0; mt < 4; ++mt)
            #pragma unroll
            for (int r = 0; r < 4; ++r) { oA[mt][r] *= alphaA; oB[mt][r] *= alphaB; }
        // ---- O^T += V^T · P^T
        #pragma unroll
        for (int mt = 0; mt < 4; ++mt) {
            oA[mt] = MFMA(v0[mt], pfA[0], oA[mt]);
            oA[mt] = MFMA(v1[mt], pfA[1], oA[mt]);
            oB[mt] = MFMA(v0[mt], pfB[0], oB[mt]);
            oB[mt] = MFMA(v1[mt], pfB[1], oB[mt]);
        }
        // ---- rotate prefetched K
        #pragma unroll
        for (int nt = 0; nt < 4; ++nt) { kc0[nt] = kn0[nt]; kc1[nt] = kn1[nt]; }
    }

    // ---- epilogue: normalize, split hi/lo bf16, store
    float invA = 1.0f / lA, invB = 1.0f / lB;
    size_t rowA = (size_t)(b * 4096 + q0 + col) * 512 + h * 64;
    size_t rowB = rowA + (size_t)16 * 512;
    #pragma unroll
    for (int mt = 0; mt < 4; ++mt) {
        float a0 = oA[mt][0] * invA, a1 = oA[mt][1] * invA;
        float a2 = oA[mt][2] * invA, a3 = oA[mt][3] * invA;
        int2 hi, lo;
        hi.x = pack2(a0, a1); hi.y = pack2(a2, a3);
        lo.x = pack2(a0 - bf2f(f2bf(a0)), a1 - bf2f(f2bf(a1)));
        lo.y = pack2(a2 - bf2f(f2bf(a2)), a3 - bf2f(f2bf(a3)));
        *(int2*)(Ahi + rowA + mt * 16 + quad * 4) = hi;
        *(int2*)(Alo + rowA + mt * 16 + quad * 4) = lo;
        float b0 = oB[mt][0] * invB, b1 = oB[mt][1] * invB;
        float b2 = oB[mt][2] * invB, b3 = oB[mt][3] * invB;
        hi.x = pack2(b0, b1); hi.y = pack2(b2, b3);
        lo.x = pack2(b0 - bf2f(f2bf(b0)), b1 - bf2f(f2bf(b1)));
        lo.y = pack2(b2 - bf2f(f2bf(b2)), b3 - bf2f(f2bf(b3)));
        *(int2*)(Ahi + rowB + mt * 16 + quad * 4) = hi;
        *(int2*)(Alo + rowB + mt * 16 + quad * 4) = lo;
    }
}

// ---------------------------------------------------------------- out GEMM
__global__ __launch_bounds__(256) void out_gemm(
    const short* __restrict__ Ahi, const short* __restrict__ Alo,
    const short* __restrict__ Whi, const short* __restrict__ Wlo,
    const float* __restrict__ bo, float* __restrict__ Out)
{
    const int lane = threadIdx.x & 63, wave = threadIdx.x >> 6;
    const int col = lane & 15, quad = lane >> 4;
    const int wm = wave & 1, wn = wave >> 1;
    const int m0 = blockIdx.x * 64 + wm * 32;
    const int n0 = blockIdx.y * 64 + wn * 32;
    floatx4 acc[2][2] = {};
    const short* ahp = Ahi + (size_t)(m0 + col) * 512 + quad * 8;
    const short* alp = Alo + (size_t)(m0 + col) * 512 + quad * 8;
    const short* bhp = Whi + (size_t)(n0 + col) * 512 + quad * 8;
    const short* blp = Wlo + (size_t)(n0 + col) * 512 + quad * 8;
    #pragma unroll 2
    for (int k = 0; k < 512; k += 32) {
        short8 ah0 = *(const short8*)(ahp + k);
        short8 ah1 = *(const short8*)(ahp + 16 * 512 + k);
        short8 al0 = *(const short8*)(alp + k);
        short8 al1 = *(const short8*)(alp + 16 * 512 + k);
        short8 bh0 = *(const short8*)(bhp + k);
        short8 bh1 = *(const short8*)(bhp + 16 * 512 + k);
        short8 bl0 = *(const short8*)(blp + k);
        short8 bl1 = *(const short8*)(blp + 16 * 512 + k);
        acc[0][0] = MFMA(ah0, bh0, acc[0][0]);
        acc[0][0] = MFMA(ah0, bl0, acc[0][0]);
        acc[0][0] = MFMA(al0, bh0, acc[0][0]);
        acc[0][1] = MFMA(ah0, bh1, acc[0][1]);
        acc[0][1] = MFMA(ah0, bl1, acc[0][1]);
        acc[0][1] = MFMA(al0, bh1, acc[0][1]);
        acc[1][0] = MFMA(ah1, bh0, acc[1][0]);
        acc[1][0] = MFMA(ah1, bl0, acc[1][0]);
        acc[1][0] = MFMA(al1, bh0, acc[1][0]);
        acc[1][1] = MFMA(ah1, bh1, acc[1][1]);
        acc[1][1] = MFMA(ah1, bl1, acc[1][1]);
        acc[1][1] = MFMA(al1, bh1, acc[1][1]);
    }
    #pragma unroll
    for (int i = 0; i < 2; ++i)
        #pragma unroll
        for (int j = 0; j < 2; ++j)
            #pragma unroll
            for (int r = 0; r < 4; ++r) {
                int m = m0 + i * 16 + quad * 4 + r;
                int n = n0 + j * 16 + col;
                Out[(size_t)m * 512 + n] = acc[i][j][r] + bo[n];
            }
}

// ---------------------------------------------------------------- launcher
extern "C" void kernel_launch(void* const* d_in, const int* in_sizes, int n_in,
                              void* d_out, int out_size, void* d_ws, size_t ws_size,
                              hipStream_t stream) {
    (void)in_sizes; (void)n_in; (void)out_size; (void)ws_size;
    const float* x   = (const float*)d_in[0];
    const float* W_q = (const float*)d_in[1];
    const float* b_q = (const float*)d_in[2];
    const float* W_k = (const float*)d_in[3];
    const float* b_k = (const float*)d_in[4];
    const float* W_v = (const float*)d_in[5];
    const float* b_v = (const float*)d_in[6];
    const float* W_o = (const float*)d_in[7];
    const float* b_o = (const float*)d_in[8];
    float* out = (float*)d_out;
    char* ws = (char*)d_ws;

    short* Xb   = (short*)(ws + 0);          // 8192*512*2  = 8,388,608
    short* Wqb  = (short*)(ws + 8388608);
    short* Wkb  = (short*)(ws + 8912896);
    short* Wvb  = (short*)(ws + 9437184);
    short* Wohi = (short*)(ws + 9961472);
    short* Wolo = (short*)(ws + 10485760);
    short* Qb   = (short*)(ws + 11010048);   // [16][4096][64]
    short* Kb   = (short*)(ws + 19398656);
    short* VTb  = (short*)(ws + 27787264);   // [16][64][4096]
    short* Ahi  = (short*)(ws + 36175872);   // [8192][512]
    short* Alo  = (short*)(ws + 44564480);   // end 52,953,088 bytes

    cvt_bf16<<<dim3(2048), dim3(256), 0, stream>>>(x, Xb, 4194304);
    cvt3_bf16<<<dim3(384), dim3(256), 0, stream>>>(W_q, W_k, W_v, Wqb, Wkb, Wvb);
    cvt_split<<<dim3(128), dim3(256), 0, stream>>>(W_o, Wohi, Wolo, 262144);
    qkv_gemm<<<dim3(128, 24), dim3(256), 0, stream>>>(Xb, Wqb, Wkb, Wvb, b_q, b_k, b_v, Qb, Kb, VTb);
    flash_attn<<<dim3(32, 16), dim3(256), 0, stream>>>(Qb, Kb, VTb, Ahi, Alo);
    out_gemm<<<dim3(128, 8), dim3(256), 0, stream>>>(Ahi, Alo, Wohi, Wolo, b_o, out);
}